// Round 4
// baseline (196.791 us; speedup 1.0000x reference)
//
#include <hip/hip_runtime.h>
#include <math.h>

#define B 4
#define NBC 128
#define HID 64
#define HC 64
#define WC 64
#define P_TOTAL (HC*WC)
#define HOUT 256
#define WOUT 256

typedef __attribute__((ext_vector_type(8)))  short bs8;   // 8 bf16 (4 VGPRs) MFMA A/B frag
typedef __attribute__((ext_vector_type(16))) float fx16;  // 32x32 MFMA C/D frag

// Fast exact-gelu: erf via 3-term Abramowitz-Stegun 7.1.25 (|err| <= 2.5e-5).
__device__ __forceinline__ float gelu_fast(float x) {
    float y = fabsf(x) * 0.70710678118654752f;
    float t = __builtin_amdgcn_rcpf(fmaf(0.47047f, y, 1.0f));
    float p = fmaf(t, 0.7478556f, -0.0958798f);
    p = fmaf(t, p, 0.3480242f);
    p = p * t;
    float e = __expf(-y * y);
    float er = fmaf(-p, e, 1.0f);
    float s = copysignf(er, x);
    float hx = 0.5f * x;
    return fmaf(hx, s, hx);
}

// fp32 -> bf16 bits, round-half-up (differs from RNE only on exact ties)
__device__ __forceinline__ short f2bf(float f) {
    return (short)((__float_as_uint(f) + 0x8000u) >> 16);
}
__device__ __forceinline__ float bf2f(short h) {
    return __uint_as_float(((unsigned)(unsigned short)h) << 16);
}

// ---------------------------------------------------------------------------
// Kernel A: per-(b,n) boundary encoder + fold bfg = bf @ g1w_f + g1b
// ---------------------------------------------------------------------------
__global__ void bg_encode(const float* __restrict__ bi,
                          const float* __restrict__ e1w, const float* __restrict__ e1b,
                          const float* __restrict__ e2w, const float* __restrict__ e2b,
                          const float* __restrict__ g1w, const float* __restrict__ g1b,
                          float* __restrict__ bfg) {
    int bn = blockIdx.x;
    int h  = threadIdx.x;
    __shared__ float t1[HID];
    __shared__ float t2[HID];
    float x = bi[bn*3+0], y = bi[bn*3+1], z = bi[bn*3+2];
    float a = x*e1w[0*HID+h] + y*e1w[1*HID+h] + z*e1w[2*HID+h] + e1b[h];
    t1[h] = gelu_fast(a);
    __syncthreads();
    float s = e2b[h];
    #pragma unroll
    for (int k = 0; k < HID; ++k) s += t1[k]*e2w[k*HID+h];
    t2[h] = gelu_fast(s);
    __syncthreads();
    float o = g1b[h];
    #pragma unroll
    for (int k = 0; k < HID; ++k) o += t2[k]*g1w[k*HID+h];
    bfg[bn*HID+h] = o;
}

// ---------------------------------------------------------------------------
// Kernel B: main contraction. Grid (128 p-tiles, B, 2 n-halves), block 256.
// Swapped MFMA: D[j][p] = (g2w^T)(h1^T)  ->  lane's C column = p = lane&31,
// so wgt(p,n) is the lane's own scalar: no cross-lane ops in the n-loop.
// Per-lane constant tables live in LDS (broadcast / conflict-free reads) to
// keep VGPR low for occupancy.
// ---------------------------------------------------------------------------
__global__ __launch_bounds__(256, 4) void bg_main(
    const float* __restrict__ bi,
    const float* __restrict__ g1w,     // rows 64,65 = g1w_c ; row 66 = g1w_d
    const float* __restrict__ g2w,     // [64][32]
    const float* __restrict__ g2b,     // [32]
    const float* __restrict__ g3w,     // [32]
    const float* __restrict__ g3b,     // [1]
    const float* __restrict__ dscale,  // [1]
    const float* __restrict__ bfg,     // [B*NBC][HID]
    float* __restrict__ ucp)           // [2][B][P_TOTAL] partials
{
    const int b    = blockIdx.y;
    const int nh   = blockIdx.z;       // n-half: 0 or 1
    const int p0   = blockIdx.x * 32;
    const int tid  = threadIdx.x;
    const int lane = tid & 63;
    const int wid  = tid >> 6;         // 0..3
    const int row  = lane & 31;        // p column of C
    const int half = lane >> 5;        // k/j sub-block

    __shared__ float s_bfg[64][HID];    // this n-half's bfg rows (16 KB)
    __shared__ float s_cg[32][65];      // cg[p][k], stride 65 -> conflict-free
    __shared__ float s_bcx[64], s_bcy[64];
    __shared__ float s_g1d[HID];
    __shared__ float s_g2b[32], s_g3w[32];
    __shared__ float s_red[4][32];

    {   // stage this n-half's bfg rows (coalesced float4)
        const float4* src = (const float4*)(bfg + (b*NBC + nh*64)*HID);
        float4* dst = (float4*)(&s_bfg[0][0]);
        #pragma unroll
        for (int i = 0; i < 4; ++i)            // 1024 float4 / 256 thr
            dst[tid + i*256] = src[tid + i*256];
    }
    if (tid < 64) {
        int ng = b*NBC + nh*64 + tid;
        s_bcx[tid] = bi[ng*3+0];
        s_bcy[tid] = bi[ng*3+1];
        s_g1d[tid] = g1w[66*HID + tid];
    }
    if (tid >= 64 && tid < 96)  s_g2b[tid-64] = g2b[tid-64];
    if (tid >= 96 && tid < 128) s_g3w[tid-96] = g3w[tid-96];
    #pragma unroll
    for (int i = 0; i < 8; ++i) {               // cg tile: 2048 items
        int idx = tid + i*256;
        int pl = idx >> 6, k = idx & 63;
        int pp = p0 + pl;
        float gxx = -1.0f + (2.0f/(WC-1)) * (float)(pp & (WC-1));
        float gyy = -1.0f + (2.0f/(HC-1)) * (float)(pp >> 6);
        s_cg[pl][k] = gxx*g1w[64*HID+k] + gyy*g1w[65*HID+k];
    }

    // g2w^T fragments (A operand), hi+lo bf16 split for accuracy
    bs8 whi[4], wlo[4];
    #pragma unroll
    for (int m = 0; m < 4; ++m) {
        #pragma unroll
        for (int e = 0; e < 8; ++e) {
            int k = m*16 + half*8 + e;
            float w = g2w[k*32 + row];
            short hi = f2bf(w);
            whi[m][e] = hi;
            wlo[m][e] = f2bf(w - bf2f(hi));
        }
    }
    __syncthreads();

    const int p = p0 + row;
    const float gx = -1.0f + (2.0f/(WC-1)) * (float)(p & (WC-1));
    const float gy = -1.0f + (2.0f/(HC-1)) * (float)(p >> 6);
    const float as = fabsf(dscale[0]);
    const float g3bias = g3b[0];

    float accp = 0.0f, wsum = 0.0f;

    for (int ni = 0; ni < 16; ++ni) {
        const int n = wid*16 + ni;              // block-local boundary index
        float dx = s_bcx[n] - gx;
        float dy = s_bcy[n] - gy;
        float dist = sqrtf(dx*dx + dy*dy + 1e-8f);
        float wgt = __expf(-as * dist);
        wsum += wgt;

        fx16 acc;                                // bias-initialized: j = q+8rr+4half
        #pragma unroll
        for (int rr = 0; rr < 4; ++rr) {
            float4 bias = *(const float4*)&s_g2b[rr*8 + half*4];
            acc[rr*4+0] = bias.x; acc[rr*4+1] = bias.y;
            acc[rr*4+2] = bias.z; acc[rr*4+3] = bias.w;
        }

        #pragma unroll
        for (int m = 0; m < 4; ++m) {
            bs8 af;                              // B operand: h1^T, col = p
            #pragma unroll
            for (int e = 0; e < 8; ++e) {
                int k = m*16 + half*8 + e;
                float u = s_bfg[n][k] + fmaf(dist, s_g1d[k], s_cg[row][k]);
                af[e] = f2bf(gelu_fast(u));
            }
            acc = __builtin_amdgcn_mfma_f32_32x32x16_bf16(whi[m], af, acc, 0, 0, 0);
            acc = __builtin_amdgcn_mfma_f32_32x32x16_bf16(wlo[m], af, acc, 0, 0, 0);
        }

        float s = 0.0f;
        #pragma unroll
        for (int rr = 0; rr < 4; ++rr) {
            float4 gw = *(const float4*)&s_g3w[rr*8 + half*4];
            s = fmaf(gelu_fast(acc[rr*4+0]), gw.x, s);
            s = fmaf(gelu_fast(acc[rr*4+1]), gw.y, s);
            s = fmaf(gelu_fast(acc[rr*4+2]), gw.z, s);
            s = fmaf(gelu_fast(acc[rr*4+3]), gw.w, s);
        }
        accp = fmaf(s, wgt, accp);
    }

    // combine the two j-halves (lane and lane^32 share the same p)
    float v = accp + __shfl_xor(accp, 32, 64);
    if (half == 0) s_red[wid][row] = fmaf(g3bias, wsum, v);
    __syncthreads();
    if (tid < 32) {
        float sum = s_red[0][tid] + s_red[1][tid] + s_red[2][tid] + s_red[3][tid];
        ucp[(nh*B + b)*P_TOTAL + p0 + tid] = sum * (1.0f/NBC);
    }
}

// ---------------------------------------------------------------------------
// Kernel C: combine n-half partials + bilinear align_corners upsample
// ---------------------------------------------------------------------------
__global__ void bg_upsample(const float* __restrict__ ucp, float* __restrict__ out) {
    int idx = blockIdx.x * 256 + threadIdx.x;
    if (idx >= B*HOUT*WOUT) return;
    int x = idx & (WOUT-1);
    int y = (idx >> 8) & (HOUT-1);
    int b = idx >> 16;
    float fy = (float)y * ((float)(HC-1)/(float)(HOUT-1));
    float fx = (float)x * ((float)(WC-1)/(float)(WOUT-1));
    int y0 = (int)floorf(fy);
    int x0 = (int)floorf(fx);
    int y1 = min(y0+1, HC-1);
    int x1 = min(x0+1, WC-1);
    float wy = fy - (float)y0;
    float wx = fx - (float)x0;
    const float* u0 = ucp + b*P_TOTAL;
    const float* u1 = ucp + (B + b)*P_TOTAL;
    float v00 = u0[y0*WC+x0] + u1[y0*WC+x0];
    float v01 = u0[y0*WC+x1] + u1[y0*WC+x1];
    float v10 = u0[y1*WC+x0] + u1[y1*WC+x0];
    float v11 = u0[y1*WC+x1] + u1[y1*WC+x1];
    float top = v00 + (v01 - v00)*wx;
    float bot = v10 + (v11 - v10)*wx;
    out[idx] = top + (bot - top)*wy;
}

extern "C" void kernel_launch(void* const* d_in, const int* in_sizes, int n_in,
                              void* d_out, int out_size, void* d_ws, size_t ws_size,
                              hipStream_t stream) {
    const float* bi  = (const float*)d_in[0];
    const float* e1w = (const float*)d_in[2];
    const float* e1b = (const float*)d_in[3];
    const float* e2w = (const float*)d_in[4];
    const float* e2b = (const float*)d_in[5];
    const float* g1w = (const float*)d_in[6];
    const float* g1b = (const float*)d_in[7];
    const float* g2w = (const float*)d_in[8];
    const float* g2b = (const float*)d_in[9];
    const float* g3w = (const float*)d_in[10];
    const float* g3b = (const float*)d_in[11];
    const float* ds  = (const float*)d_in[12];
    float* out = (float*)d_out;

    float* bfg = (float*)d_ws;                 // B*NBC*HID floats
    float* ucp = bfg + B*NBC*HID;              // 2*B*P_TOTAL floats (partials)

    bg_encode<<<dim3(B*NBC), dim3(64), 0, stream>>>(bi, e1w, e1b, e2w, e2b, g1w, g1b, bfg);
    bg_main<<<dim3(P_TOTAL/32, B, 2), dim3(256), 0, stream>>>(bi, g1w, g2w, g2b, g3w, g3b, ds, bfg, ucp);
    bg_upsample<<<dim3((B*HOUT*WOUT)/256), dim3(256), 0, stream>>>(ucp, out);
}

// Round 5
// 104.565 us; speedup vs baseline: 1.8820x; 1.8820x over previous
//
#include <hip/hip_runtime.h>
#include <math.h>

#define B 4
#define NBC 128
#define HID 64
#define HC 64
#define WC 64
#define P_TOTAL (HC*WC)
#define HOUT 256
#define WOUT 256

typedef __attribute__((ext_vector_type(8)))  short bs8;   // 8 bf16 (4 VGPRs) MFMA A/B frag
typedef __attribute__((ext_vector_type(16))) float fx16;  // 32x32 MFMA C/D frag

// Fast exact-gelu: erf via 3-term Abramowitz-Stegun 7.1.25 (|err| <= 2.5e-5).
__device__ __forceinline__ float gelu_fast(float x) {
    float y = fabsf(x) * 0.70710678118654752f;
    float t = __builtin_amdgcn_rcpf(fmaf(0.47047f, y, 1.0f));
    float p = fmaf(t, 0.7478556f, -0.0958798f);
    p = fmaf(t, p, 0.3480242f);
    p = p * t;
    float e = __expf(-y * y);
    float er = fmaf(-p, e, 1.0f);
    float s = copysignf(er, x);
    float hx = 0.5f * x;
    return fmaf(hx, s, hx);
}

// fp32 -> bf16 bits, round-half-up (differs from RNE only on exact ties)
__device__ __forceinline__ short f2bf(float f) {
    return (short)((__float_as_uint(f) + 0x8000u) >> 16);
}
__device__ __forceinline__ float bf2f(short h) {
    return __uint_as_float(((unsigned)(unsigned short)h) << 16);
}

// ---------------------------------------------------------------------------
// Kernel A: per-(b,n) boundary encoder + fold bfg = bf @ g1w_f + g1b
// ---------------------------------------------------------------------------
__global__ void bg_encode(const float* __restrict__ bi,
                          const float* __restrict__ e1w, const float* __restrict__ e1b,
                          const float* __restrict__ e2w, const float* __restrict__ e2b,
                          const float* __restrict__ g1w, const float* __restrict__ g1b,
                          float* __restrict__ bfg) {
    int bn = blockIdx.x;
    int h  = threadIdx.x;
    __shared__ float t1[HID];
    __shared__ float t2[HID];
    float x = bi[bn*3+0], y = bi[bn*3+1], z = bi[bn*3+2];
    float a = x*e1w[0*HID+h] + y*e1w[1*HID+h] + z*e1w[2*HID+h] + e1b[h];
    t1[h] = gelu_fast(a);
    __syncthreads();
    float s = e2b[h];
    #pragma unroll
    for (int k = 0; k < HID; ++k) s += t1[k]*e2w[k*HID+h];
    t2[h] = gelu_fast(s);
    __syncthreads();
    float o = g1b[h];
    #pragma unroll
    for (int k = 0; k < HID; ++k) o += t2[k]*g1w[k*HID+h];
    bfg[bn*HID+h] = o;
}

// ---------------------------------------------------------------------------
// Kernel B: main contraction. Grid (128 p-tiles, B, 2 n-halves), block 256.
// Swapped MFMA: D[j][p] = (g2w^T)(h1^T)  ->  lane's C column = p = lane&31,
// so wgt(p,n) is the lane's own scalar: no cross-lane ops in the n-loop.
// launch_bounds(256,2): round-4's (256,4) forced whi/wlo spill to scratch
// (FETCH 551 MB/dispatch, reload per n-iter). Cap 256 VGPR -> no spill.
// ---------------------------------------------------------------------------
__global__ __launch_bounds__(256, 2) void bg_main(
    const float* __restrict__ bi,
    const float* __restrict__ g1w,     // rows 64,65 = g1w_c ; row 66 = g1w_d
    const float* __restrict__ g2w,     // [64][32]
    const float* __restrict__ g2b,     // [32]
    const float* __restrict__ g3w,     // [32]
    const float* __restrict__ g3b,     // [1]
    const float* __restrict__ dscale,  // [1]
    const float* __restrict__ bfg,     // [B*NBC][HID]
    float* __restrict__ ucp)           // [2][B][P_TOTAL] partials
{
    const int b    = blockIdx.y;
    const int nh   = blockIdx.z;       // n-half: 0 or 1
    const int p0   = blockIdx.x * 32;
    const int tid  = threadIdx.x;
    const int lane = tid & 63;
    const int wid  = tid >> 6;         // 0..3
    const int row  = lane & 31;        // p column of C
    const int half = lane >> 5;        // k/j sub-block

    __shared__ float s_bfg[64][HID];    // this n-half's bfg rows (16 KB)
    __shared__ float s_cg[32][65];      // cg[p][k], stride 65 -> conflict-free
    __shared__ float s_bcx[64], s_bcy[64];
    __shared__ float s_g1d[HID];
    __shared__ float s_g2b[32], s_g3w[32];
    __shared__ float s_red[4][32];

    {   // stage this n-half's bfg rows (coalesced float4)
        const float4* src = (const float4*)(bfg + (b*NBC + nh*64)*HID);
        float4* dst = (float4*)(&s_bfg[0][0]);
        #pragma unroll
        for (int i = 0; i < 4; ++i)            // 1024 float4 / 256 thr
            dst[tid + i*256] = src[tid + i*256];
    }
    if (tid < 64) {
        int ng = b*NBC + nh*64 + tid;
        s_bcx[tid] = bi[ng*3+0];
        s_bcy[tid] = bi[ng*3+1];
        s_g1d[tid] = g1w[66*HID + tid];
    }
    if (tid >= 64 && tid < 96)  s_g2b[tid-64] = g2b[tid-64];
    if (tid >= 96 && tid < 128) s_g3w[tid-96] = g3w[tid-96];
    #pragma unroll
    for (int i = 0; i < 8; ++i) {               // cg tile: 2048 items
        int idx = tid + i*256;
        int pl = idx >> 6, k = idx & 63;
        int pp = p0 + pl;
        float gxx = -1.0f + (2.0f/(WC-1)) * (float)(pp & (WC-1));
        float gyy = -1.0f + (2.0f/(HC-1)) * (float)(pp >> 6);
        s_cg[pl][k] = gxx*g1w[64*HID+k] + gyy*g1w[65*HID+k];
    }

    // g2w^T fragments (A operand), hi+lo bf16 split for accuracy
    bs8 whi[4], wlo[4];
    #pragma unroll
    for (int m = 0; m < 4; ++m) {
        #pragma unroll
        for (int e = 0; e < 8; ++e) {
            int k = m*16 + half*8 + e;
            float w = g2w[k*32 + row];
            short hi = f2bf(w);
            whi[m][e] = hi;
            wlo[m][e] = f2bf(w - bf2f(hi));
        }
    }
    __syncthreads();

    const int p = p0 + row;
    const float gx = -1.0f + (2.0f/(WC-1)) * (float)(p & (WC-1));
    const float gy = -1.0f + (2.0f/(HC-1)) * (float)(p >> 6);
    const float as = fabsf(dscale[0]);
    const float g3bias = g3b[0];

    float accp = 0.0f, wsum = 0.0f;

    for (int ni = 0; ni < 16; ++ni) {
        const int n = wid*16 + ni;              // block-local boundary index
        float dx = s_bcx[n] - gx;
        float dy = s_bcy[n] - gy;
        float dist = sqrtf(dx*dx + dy*dy + 1e-8f);
        float wgt = __expf(-as * dist);
        wsum += wgt;

        fx16 acc;                                // bias-initialized: j = q+8rr+4half
        #pragma unroll
        for (int rr = 0; rr < 4; ++rr) {
            float4 bias = *(const float4*)&s_g2b[rr*8 + half*4];
            acc[rr*4+0] = bias.x; acc[rr*4+1] = bias.y;
            acc[rr*4+2] = bias.z; acc[rr*4+3] = bias.w;
        }

        #pragma unroll
        for (int m = 0; m < 4; ++m) {
            bs8 af;                              // B operand: h1^T, col = p
            #pragma unroll
            for (int e = 0; e < 8; ++e) {
                int k = m*16 + half*8 + e;
                float u = s_bfg[n][k] + fmaf(dist, s_g1d[k], s_cg[row][k]);
                af[e] = f2bf(gelu_fast(u));
            }
            acc = __builtin_amdgcn_mfma_f32_32x32x16_bf16(whi[m], af, acc, 0, 0, 0);
            acc = __builtin_amdgcn_mfma_f32_32x32x16_bf16(wlo[m], af, acc, 0, 0, 0);
        }

        float s = 0.0f;
        #pragma unroll
        for (int rr = 0; rr < 4; ++rr) {
            float4 gw = *(const float4*)&s_g3w[rr*8 + half*4];
            s = fmaf(gelu_fast(acc[rr*4+0]), gw.x, s);
            s = fmaf(gelu_fast(acc[rr*4+1]), gw.y, s);
            s = fmaf(gelu_fast(acc[rr*4+2]), gw.z, s);
            s = fmaf(gelu_fast(acc[rr*4+3]), gw.w, s);
        }
        accp = fmaf(s, wgt, accp);
    }

    // combine the two j-halves (lane and lane^32 share the same p)
    float v = accp + __shfl_xor(accp, 32, 64);
    if (half == 0) s_red[wid][row] = fmaf(g3bias, wsum, v);
    __syncthreads();
    if (tid < 32) {
        float sum = s_red[0][tid] + s_red[1][tid] + s_red[2][tid] + s_red[3][tid];
        ucp[(nh*B + b)*P_TOTAL + p0 + tid] = sum * (1.0f/NBC);
    }
}

// ---------------------------------------------------------------------------
// Kernel C: combine n-half partials + bilinear align_corners upsample
// ---------------------------------------------------------------------------
__global__ void bg_upsample(const float* __restrict__ ucp, float* __restrict__ out) {
    int idx = blockIdx.x * 256 + threadIdx.x;
    if (idx >= B*HOUT*WOUT) return;
    int x = idx & (WOUT-1);
    int y = (idx >> 8) & (HOUT-1);
    int b = idx >> 16;
    float fy = (float)y * ((float)(HC-1)/(float)(HOUT-1));
    float fx = (float)x * ((float)(WC-1)/(float)(WOUT-1));
    int y0 = (int)floorf(fy);
    int x0 = (int)floorf(fx);
    int y1 = min(y0+1, HC-1);
    int x1 = min(x0+1, WC-1);
    float wy = fy - (float)y0;
    float wx = fx - (float)x0;
    const float* u0 = ucp + b*P_TOTAL;
    const float* u1 = ucp + (B + b)*P_TOTAL;
    float v00 = u0[y0*WC+x0] + u1[y0*WC+x0];
    float v01 = u0[y0*WC+x1] + u1[y0*WC+x1];
    float v10 = u0[y1*WC+x0] + u1[y1*WC+x0];
    float v11 = u0[y1*WC+x1] + u1[y1*WC+x1];
    float top = v00 + (v01 - v00)*wx;
    float bot = v10 + (v11 - v10)*wx;
    out[idx] = top + (bot - top)*wy;
}

extern "C" void kernel_launch(void* const* d_in, const int* in_sizes, int n_in,
                              void* d_out, int out_size, void* d_ws, size_t ws_size,
                              hipStream_t stream) {
    const float* bi  = (const float*)d_in[0];
    const float* e1w = (const float*)d_in[2];
    const float* e1b = (const float*)d_in[3];
    const float* e2w = (const float*)d_in[4];
    const float* e2b = (const float*)d_in[5];
    const float* g1w = (const float*)d_in[6];
    const float* g1b = (const float*)d_in[7];
    const float* g2w = (const float*)d_in[8];
    const float* g2b = (const float*)d_in[9];
    const float* g3w = (const float*)d_in[10];
    const float* g3b = (const float*)d_in[11];
    const float* ds  = (const float*)d_in[12];
    float* out = (float*)d_out;

    float* bfg = (float*)d_ws;                 // B*NBC*HID floats
    float* ucp = bfg + B*NBC*HID;              // 2*B*P_TOTAL floats (partials)

    bg_encode<<<dim3(B*NBC), dim3(64), 0, stream>>>(bi, e1w, e1b, e2w, e2b, g1w, g1b, bfg);
    bg_main<<<dim3(P_TOTAL/32, B, 2), dim3(256), 0, stream>>>(bi, g1w, g2w, g2b, g3w, g3b, ds, bfg, ucp);
    bg_upsample<<<dim3((B*HOUT*WOUT)/256), dim3(256), 0, stream>>>(ucp, out);
}

// Round 6
// 90.469 us; speedup vs baseline: 2.1752x; 1.1558x over previous
//
#include <hip/hip_runtime.h>
#include <math.h>

#define B 4
#define NBC 128
#define HID 64
#define HC 64
#define WC 64
#define P_TOTAL (HC*WC)
#define HOUT 256
#define WOUT 256

typedef __attribute__((ext_vector_type(8)))  short bs8;   // 8 bf16 (4 VGPRs) MFMA A/B frag
typedef __attribute__((ext_vector_type(16))) float fx16;  // 32x32 MFMA C/D frag

// Fast exact-gelu: erf via 3-term Abramowitz-Stegun 7.1.25 (|err| <= 2.5e-5).
// Used in bg_encode and to build the LUT nodes.
__device__ __forceinline__ float gelu_fast(float x) {
    float y = fabsf(x) * 0.70710678118654752f;
    float t = __builtin_amdgcn_rcpf(fmaf(0.47047f, y, 1.0f));
    float p = fmaf(t, 0.7478556f, -0.0958798f);
    p = fmaf(t, p, 0.3480242f);
    p = p * t;
    float e = __expf(-y * y);
    float er = fmaf(-p, e, 1.0f);
    float s = copysignf(er, x);
    float hx = 0.5f * x;
    return fmaf(hx, s, hx);
}

// LDS lookup-table gelu: [-8,8] in 2048 steps (h=1/128), linear interp.
// Interp err <= 8.4e-6; low tail (x<-8) handled by clamp (T[0]=gelu(-8)~0),
// high tail via cndmask. ~10 full-rate VALU ops + 1 ds_read2_b32 vs ~36 cyc
// for the arithmetic version (rcp+exp transcendentals eliminated).
__device__ __forceinline__ float gelu_lut(float x, const float* __restrict__ lut) {
    float xi = fmaf(x, 128.0f, 1024.0f);
    xi = fminf(fmaxf(xi, 0.0f), 2047.99f);
    int i = (int)xi;
    float f = xi - (float)i;
    float a = lut[i];
    float b = lut[i + 1];
    float v = fmaf(f, b - a, a);
    return (x > 8.0f) ? x : v;
}

// fp32 -> bf16 bits, round-half-up
__device__ __forceinline__ short f2bf(float f) {
    return (short)((__float_as_uint(f) + 0x8000u) >> 16);
}
__device__ __forceinline__ float bf2f(short h) {
    return __uint_as_float(((unsigned)(unsigned short)h) << 16);
}

// ---------------------------------------------------------------------------
// Kernel A: per-(b,n) boundary encoder + fold bfg = bf @ g1w_f + g1b
// ---------------------------------------------------------------------------
__global__ void bg_encode(const float* __restrict__ bi,
                          const float* __restrict__ e1w, const float* __restrict__ e1b,
                          const float* __restrict__ e2w, const float* __restrict__ e2b,
                          const float* __restrict__ g1w, const float* __restrict__ g1b,
                          float* __restrict__ bfg) {
    int bn = blockIdx.x;
    int h  = threadIdx.x;
    __shared__ float t1[HID];
    __shared__ float t2[HID];
    float x = bi[bn*3+0], y = bi[bn*3+1], z = bi[bn*3+2];
    float a = x*e1w[0*HID+h] + y*e1w[1*HID+h] + z*e1w[2*HID+h] + e1b[h];
    t1[h] = gelu_fast(a);
    __syncthreads();
    float s = e2b[h];
    #pragma unroll
    for (int k = 0; k < HID; ++k) s += t1[k]*e2w[k*HID+h];
    t2[h] = gelu_fast(s);
    __syncthreads();
    float o = g1b[h];
    #pragma unroll
    for (int k = 0; k < HID; ++k) o += t2[k]*g1w[k*HID+h];
    bfg[bn*HID+h] = o;
}

// ---------------------------------------------------------------------------
// Kernel B: main contraction. Grid (128 p-tiles, B, 2 n-halves), block 256.
// Swapped MFMA: D[j][p] = (g2w^T)(h1^T) -> lane's C column = p = lane&31.
// gelu via per-block LDS LUT (both h1 and h2 activations).
// launch_bounds(256,2): (256,4) caused scratch spill (round 4).
// ---------------------------------------------------------------------------
__global__ __launch_bounds__(256, 2) void bg_main(
    const float* __restrict__ bi,
    const float* __restrict__ g1w,     // rows 64,65 = g1w_c ; row 66 = g1w_d
    const float* __restrict__ g2w,     // [64][32]
    const float* __restrict__ g2b,     // [32]
    const float* __restrict__ g3w,     // [32]
    const float* __restrict__ g3b,     // [1]
    const float* __restrict__ dscale,  // [1]
    const float* __restrict__ bfg,     // [B*NBC][HID]
    float* __restrict__ ucp)           // [2][B][P_TOTAL] partials
{
    const int b    = blockIdx.y;
    const int nh   = blockIdx.z;       // n-half: 0 or 1
    const int p0   = blockIdx.x * 32;
    const int tid  = threadIdx.x;
    const int lane = tid & 63;
    const int wid  = tid >> 6;         // 0..3
    const int row  = lane & 31;        // p column of C
    const int half = lane >> 5;        // k/j sub-block

    __shared__ float s_bfg[64][HID];    // this n-half's bfg rows (16 KB)
    __shared__ float s_cg[32][65];      // cg[p][k], stride 65 -> conflict-free
    __shared__ float s_lut[2049];       // gelu table (8.2 KB)
    __shared__ float s_bcx[64], s_bcy[64];
    __shared__ float s_g1d[HID];
    __shared__ float s_g2b[32], s_g3w[32];
    __shared__ float s_red[4][32];

    {   // stage this n-half's bfg rows (coalesced float4)
        const float4* src = (const float4*)(bfg + (b*NBC + nh*64)*HID);
        float4* dst = (float4*)(&s_bfg[0][0]);
        #pragma unroll
        for (int i = 0; i < 4; ++i)
            dst[tid + i*256] = src[tid + i*256];
    }
    if (tid < 64) {
        int ng = b*NBC + nh*64 + tid;
        s_bcx[tid] = bi[ng*3+0];
        s_bcy[tid] = bi[ng*3+1];
        s_g1d[tid] = g1w[66*HID + tid];
    }
    if (tid >= 64 && tid < 96)  s_g2b[tid-64] = g2b[tid-64];
    if (tid >= 96 && tid < 128) s_g3w[tid-96] = g3w[tid-96];
    #pragma unroll
    for (int i = 0; i < 8; ++i) {               // cg tile: 2048 items
        int idx = tid + i*256;
        int pl = idx >> 6, k = idx & 63;
        int pp = p0 + pl;
        float gxx = -1.0f + (2.0f/(WC-1)) * (float)(pp & (WC-1));
        float gyy = -1.0f + (2.0f/(HC-1)) * (float)(pp >> 6);
        s_cg[pl][k] = gxx*g1w[64*HID+k] + gyy*g1w[65*HID+k];
    }
    for (int i = tid; i < 2049; i += 256)       // gelu LUT build
        s_lut[i] = gelu_fast(fmaf((float)i, 0.0078125f, -8.0f));

    // g2w^T fragments (A operand), hi+lo bf16 split for accuracy
    bs8 whi[4], wlo[4];
    #pragma unroll
    for (int m = 0; m < 4; ++m) {
        #pragma unroll
        for (int e = 0; e < 8; ++e) {
            int k = m*16 + half*8 + e;
            float w = g2w[k*32 + row];
            short hi = f2bf(w);
            whi[m][e] = hi;
            wlo[m][e] = f2bf(w - bf2f(hi));
        }
    }
    __syncthreads();

    const int p = p0 + row;
    const float gx = -1.0f + (2.0f/(WC-1)) * (float)(p & (WC-1));
    const float gy = -1.0f + (2.0f/(HC-1)) * (float)(p >> 6);
    const float as = fabsf(dscale[0]);
    const float g3bias = g3b[0];

    float accp = 0.0f, wsum = 0.0f;

    for (int ni = 0; ni < 16; ++ni) {
        const int n = wid*16 + ni;              // block-local boundary index
        float dx = s_bcx[n] - gx;
        float dy = s_bcy[n] - gy;
        float dist = sqrtf(dx*dx + dy*dy + 1e-8f);
        float wgt = __expf(-as * dist);
        wsum += wgt;

        fx16 acc;                                // bias-initialized: j = q+8rr+4half
        #pragma unroll
        for (int rr = 0; rr < 4; ++rr) {
            float4 bias = *(const float4*)&s_g2b[rr*8 + half*4];
            acc[rr*4+0] = bias.x; acc[rr*4+1] = bias.y;
            acc[rr*4+2] = bias.z; acc[rr*4+3] = bias.w;
        }

        #pragma unroll
        for (int m = 0; m < 4; ++m) {
            bs8 af;                              // B operand: h1^T, col = p
            #pragma unroll
            for (int e = 0; e < 8; ++e) {
                int k = m*16 + half*8 + e;
                float u = s_bfg[n][k] + fmaf(dist, s_g1d[k], s_cg[row][k]);
                af[e] = f2bf(gelu_lut(u, s_lut));
            }
            acc = __builtin_amdgcn_mfma_f32_32x32x16_bf16(whi[m], af, acc, 0, 0, 0);
            acc = __builtin_amdgcn_mfma_f32_32x32x16_bf16(wlo[m], af, acc, 0, 0, 0);
        }

        float s = 0.0f;
        #pragma unroll
        for (int rr = 0; rr < 4; ++rr) {
            float4 gw = *(const float4*)&s_g3w[rr*8 + half*4];
            s = fmaf(gelu_lut(acc[rr*4+0], s_lut), gw.x, s);
            s = fmaf(gelu_lut(acc[rr*4+1], s_lut), gw.y, s);
            s = fmaf(gelu_lut(acc[rr*4+2], s_lut), gw.z, s);
            s = fmaf(gelu_lut(acc[rr*4+3], s_lut), gw.w, s);
        }
        accp = fmaf(s, wgt, accp);
    }

    // combine the two j-halves (lane and lane^32 share the same p)
    float v = accp + __shfl_xor(accp, 32, 64);
    if (half == 0) s_red[wid][row] = fmaf(g3bias, wsum, v);
    __syncthreads();
    if (tid < 32) {
        float sum = s_red[0][tid] + s_red[1][tid] + s_red[2][tid] + s_red[3][tid];
        ucp[(nh*B + b)*P_TOTAL + p0 + tid] = sum * (1.0f/NBC);
    }
}

// ---------------------------------------------------------------------------
// Kernel C: combine n-half partials + bilinear align_corners upsample
// ---------------------------------------------------------------------------
__global__ void bg_upsample(const float* __restrict__ ucp, float* __restrict__ out) {
    int idx = blockIdx.x * 256 + threadIdx.x;
    if (idx >= B*HOUT*WOUT) return;
    int x = idx & (WOUT-1);
    int y = (idx >> 8) & (HOUT-1);
    int b = idx >> 16;
    float fy = (float)y * ((float)(HC-1)/(float)(HOUT-1));
    float fx = (float)x * ((float)(WC-1)/(float)(WOUT-1));
    int y0 = (int)floorf(fy);
    int x0 = (int)floorf(fx);
    int y1 = min(y0+1, HC-1);
    int x1 = min(x0+1, WC-1);
    float wy = fy - (float)y0;
    float wx = fx - (float)x0;
    const float* u0 = ucp + b*P_TOTAL;
    const float* u1 = ucp + (B + b)*P_TOTAL;
    float v00 = u0[y0*WC+x0] + u1[y0*WC+x0];
    float v01 = u0[y0*WC+x1] + u1[y0*WC+x1];
    float v10 = u0[y1*WC+x0] + u1[y1*WC+x0];
    float v11 = u0[y1*WC+x1] + u1[y1*WC+x1];
    float top = v00 + (v01 - v00)*wx;
    float bot = v10 + (v11 - v10)*wx;
    out[idx] = top + (bot - top)*wy;
}

extern "C" void kernel_launch(void* const* d_in, const int* in_sizes, int n_in,
                              void* d_out, int out_size, void* d_ws, size_t ws_size,
                              hipStream_t stream) {
    const float* bi  = (const float*)d_in[0];
    const float* e1w = (const float*)d_in[2];
    const float* e1b = (const float*)d_in[3];
    const float* e2w = (const float*)d_in[4];
    const float* e2b = (const float*)d_in[5];
    const float* g1w = (const float*)d_in[6];
    const float* g1b = (const float*)d_in[7];
    const float* g2w = (const float*)d_in[8];
    const float* g2b = (const float*)d_in[9];
    const float* g3w = (const float*)d_in[10];
    const float* g3b = (const float*)d_in[11];
    const float* ds  = (const float*)d_in[12];
    float* out = (float*)d_out;

    float* bfg = (float*)d_ws;                 // B*NBC*HID floats
    float* ucp = bfg + B*NBC*HID;              // 2*B*P_TOTAL floats (partials)

    bg_encode<<<dim3(B*NBC), dim3(64), 0, stream>>>(bi, e1w, e1b, e2w, e2b, g1w, g1b, bfg);
    bg_main<<<dim3(P_TOTAL/32, B, 2), dim3(256), 0, stream>>>(bi, g1w, g2w, g2b, g3w, g3b, ds, bfg, ucp);
    bg_upsample<<<dim3((B*HOUT*WOUT)/256), dim3(256), 0, stream>>>(ucp, out);
}

// Round 7
// 75.746 us; speedup vs baseline: 2.5980x; 1.1944x over previous
//
#include <hip/hip_runtime.h>
#include <math.h>

#define B 4
#define NBC 128
#define HID 64
#define HC 64
#define WC 64
#define P_TOTAL (HC*WC)
#define HOUT 256
#define WOUT 256

typedef __attribute__((ext_vector_type(8)))  short bs8;   // 8 bf16 (4 VGPRs) MFMA A/B frag
typedef __attribute__((ext_vector_type(16))) float fx16;  // 32x32 MFMA C/D frag

// Fast exact-gelu: erf via 3-term Abramowitz-Stegun 7.1.25 (|err| <= 2.5e-5).
// Used in bg_encode and to build the LUT nodes.
__device__ __forceinline__ float gelu_fast(float x) {
    float y = fabsf(x) * 0.70710678118654752f;
    float t = __builtin_amdgcn_rcpf(fmaf(0.47047f, y, 1.0f));
    float p = fmaf(t, 0.7478556f, -0.0958798f);
    p = fmaf(t, p, 0.3480242f);
    p = p * t;
    float e = __expf(-y * y);
    float er = fmaf(-p, e, 1.0f);
    float s = copysignf(er, x);
    float hx = 0.5f * x;
    return fmaf(hx, s, hx);
}

// h1 path: nearest-node table returning bf16 BITS directly (no interp, no f2bf).
// 4096 nodes over [-8,8), h=1/256, nodes half-shifted so truncation == nearest.
// err <= 2.1e-3 (node spacing) + 3.9e-3 (bf16), quasi-random over n.
__device__ __forceinline__ unsigned gelu_bf16_lut(float x, const unsigned short* __restrict__ lut) {
    float xi = fmaf(x, 256.0f, 2048.0f);
    xi = fminf(fmaxf(xi, 0.0f), 4095.0f);          // v_med3
    unsigned v = lut[(int)xi];                      // ds_read_u16, zero-extended
    unsigned fb = (__float_as_uint(x) + 0x8000u) >> 16;   // bf16(x): tail x>8 where gelu(x)~=x
    return (x > 8.0f) ? fb : v;
}

// epilogue path: f32 linear interp, 1025 nodes over [-8,8], h=1/64.
// interp err <= |gelu''|max*h^2/8 ~= 2.4e-5.
__device__ __forceinline__ float gelu_interp(float x, const float* __restrict__ lut) {
    float xi = fmaf(x, 64.0f, 512.0f);
    xi = fminf(fmaxf(xi, 0.0f), 1023.99f);
    int i = (int)xi;
    float f = __builtin_amdgcn_fractf(xi);
    float a = lut[i];
    float b = lut[i + 1];
    float v = fmaf(f, b - a, a);
    return (x > 8.0f) ? x : v;
}

// fp32 -> bf16 bits, round-half-up
__device__ __forceinline__ short f2bf(float f) {
    return (short)((__float_as_uint(f) + 0x8000u) >> 16);
}
__device__ __forceinline__ float bf2f(short h) {
    return __uint_as_float(((unsigned)(unsigned short)h) << 16);
}

// ---------------------------------------------------------------------------
// Kernel A: per-(b,n) boundary encoder + fold bfg = bf @ g1w_f + g1b
// ---------------------------------------------------------------------------
__global__ void bg_encode(const float* __restrict__ bi,
                          const float* __restrict__ e1w, const float* __restrict__ e1b,
                          const float* __restrict__ e2w, const float* __restrict__ e2b,
                          const float* __restrict__ g1w, const float* __restrict__ g1b,
                          float* __restrict__ bfg) {
    int bn = blockIdx.x;
    int h  = threadIdx.x;
    __shared__ float t1[HID];
    __shared__ float t2[HID];
    float x = bi[bn*3+0], y = bi[bn*3+1], z = bi[bn*3+2];
    float a = x*e1w[0*HID+h] + y*e1w[1*HID+h] + z*e1w[2*HID+h] + e1b[h];
    t1[h] = gelu_fast(a);
    __syncthreads();
    float s = e2b[h];
    #pragma unroll
    for (int k = 0; k < HID; ++k) s += t1[k]*e2w[k*HID+h];
    t2[h] = gelu_fast(s);
    __syncthreads();
    float o = g1b[h];
    #pragma unroll
    for (int k = 0; k < HID; ++k) o += t2[k]*g1w[k*HID+h];
    bfg[bn*HID+h] = o;
}

// ---------------------------------------------------------------------------
// Kernel B: main contraction. Grid (128 p-tiles, B, 2 n-halves), block 256.
// Swapped MFMA: D[j][p] = (g2w^T)(h1^T) -> lane's C column = p = lane&31.
// h1 gelu: nearest-bf16-bits LDS LUT (single ds_read_u16, free packing).
// h2 gelu: coarse f32 interp LUT. Two independent MFMA acc chains (hi/lo
// weight split) to halve dependency depth. launch_bounds(256,2): (256,4)
// caused scratch spill (round 4). VGPR must stay <=128 for 4 waves/SIMD.
// ---------------------------------------------------------------------------
__global__ __launch_bounds__(256, 2) void bg_main(
    const float* __restrict__ bi,
    const float* __restrict__ g1w,     // rows 64,65 = g1w_c ; row 66 = g1w_d
    const float* __restrict__ g2w,     // [64][32]
    const float* __restrict__ g2b,     // [32]
    const float* __restrict__ g3w,     // [32]
    const float* __restrict__ g3b,     // [1]
    const float* __restrict__ dscale,  // [1]
    const float* __restrict__ bfg,     // [B*NBC][HID]
    float* __restrict__ ucp)           // [2][B][P_TOTAL] partials
{
    const int b    = blockIdx.y;
    const int nh   = blockIdx.z;       // n-half: 0 or 1
    const int p0   = blockIdx.x * 32;
    const int tid  = threadIdx.x;
    const int lane = tid & 63;
    const int wid  = tid >> 6;         // 0..3
    const int row  = lane & 31;        // p column of C
    const int half = lane >> 5;        // k/j sub-block

    __shared__ float s_bfg[64][HID];           // 16 KB
    __shared__ float s_cg[32][65];             // 8.32 KB, conflict-free
    __shared__ unsigned short s_lut16[4096];   // 8 KB: bf16-bits gelu, nearest
    __shared__ float s_lutf[1025];             // 4.1 KB: f32 gelu, interp
    __shared__ float s_bcx[64], s_bcy[64];
    __shared__ float s_g1d[HID];
    __shared__ float s_g2b[32], s_g3w[32];
    __shared__ float s_red[4][32];

    {   // stage this n-half's bfg rows (coalesced float4)
        const float4* src = (const float4*)(bfg + (b*NBC + nh*64)*HID);
        float4* dst = (float4*)(&s_bfg[0][0]);
        #pragma unroll
        for (int i = 0; i < 4; ++i)
            dst[tid + i*256] = src[tid + i*256];
    }
    if (tid < 64) {
        int ng = b*NBC + nh*64 + tid;
        s_bcx[tid] = bi[ng*3+0];
        s_bcy[tid] = bi[ng*3+1];
        s_g1d[tid] = g1w[66*HID + tid];
    }
    if (tid >= 64 && tid < 96)  s_g2b[tid-64] = g2b[tid-64];
    if (tid >= 96 && tid < 128) s_g3w[tid-96] = g3w[tid-96];
    #pragma unroll
    for (int i = 0; i < 8; ++i) {               // cg tile: 2048 items
        int idx = tid + i*256;
        int pl = idx >> 6, k = idx & 63;
        int pp = p0 + pl;
        float gxx = -1.0f + (2.0f/(WC-1)) * (float)(pp & (WC-1));
        float gyy = -1.0f + (2.0f/(HC-1)) * (float)(pp >> 6);
        s_cg[pl][k] = gxx*g1w[64*HID+k] + gyy*g1w[65*HID+k];
    }
    #pragma unroll
    for (int i = 0; i < 16; ++i) {              // bf16 nearest table (half-shifted nodes)
        int idx = tid + i*256;
        float node = fmaf((float)idx, 0.00390625f, -7.998046875f);  // -8 + (i+0.5)/256
        s_lut16[idx] = (unsigned short)((__float_as_uint(gelu_fast(node)) + 0x8000u) >> 16);
    }
    for (int i = tid; i < 1025; i += 256)       // f32 interp table
        s_lutf[i] = gelu_fast(fmaf((float)i, 0.015625f, -8.0f));

    // g2w^T fragments (A operand), hi+lo bf16 split for accuracy
    bs8 whi[4], wlo[4];
    #pragma unroll
    for (int m = 0; m < 4; ++m) {
        #pragma unroll
        for (int e = 0; e < 8; ++e) {
            int k = m*16 + half*8 + e;
            float w = g2w[k*32 + row];
            short hi = f2bf(w);
            whi[m][e] = hi;
            wlo[m][e] = f2bf(w - bf2f(hi));
        }
    }
    __syncthreads();

    const int p = p0 + row;
    const float gx = -1.0f + (2.0f/(WC-1)) * (float)(p & (WC-1));
    const float gy = -1.0f + (2.0f/(HC-1)) * (float)(p >> 6);
    const float as = fabsf(dscale[0]);
    const float g3bias = g3b[0];

    float accp = 0.0f, wsum = 0.0f;

    for (int ni = 0; ni < 16; ++ni) {
        const int n = wid*16 + ni;              // block-local boundary index
        float dx = s_bcx[n] - gx;
        float dy = s_bcy[n] - gy;
        float dist = sqrtf(dx*dx + dy*dy + 1e-8f);
        float wgt = __expf(-as * dist);
        wsum += wgt;

        fx16 acch, accl;                         // two independent chains
        #pragma unroll
        for (int rr = 0; rr < 4; ++rr) {
            float4 bias = *(const float4*)&s_g2b[rr*8 + half*4];
            acch[rr*4+0] = bias.x; acch[rr*4+1] = bias.y;
            acch[rr*4+2] = bias.z; acch[rr*4+3] = bias.w;
            accl[rr*4+0] = 0.0f;  accl[rr*4+1] = 0.0f;
            accl[rr*4+2] = 0.0f;  accl[rr*4+3] = 0.0f;
        }

        #pragma unroll
        for (int m = 0; m < 4; ++m) {
            bs8 af;                              // B operand: h1^T, col = p
            #pragma unroll
            for (int e = 0; e < 8; ++e) {
                int k = m*16 + half*8 + e;
                float u = s_bfg[n][k] + fmaf(dist, s_g1d[k], s_cg[row][k]);
                af[e] = (short)gelu_bf16_lut(u, s_lut16);
            }
            acch = __builtin_amdgcn_mfma_f32_32x32x16_bf16(whi[m], af, acch, 0, 0, 0);
            accl = __builtin_amdgcn_mfma_f32_32x32x16_bf16(wlo[m], af, accl, 0, 0, 0);
        }

        float s = 0.0f;
        #pragma unroll
        for (int rr = 0; rr < 4; ++rr) {
            float4 gw = *(const float4*)&s_g3w[rr*8 + half*4];
            s = fmaf(gelu_interp(acch[rr*4+0] + accl[rr*4+0], s_lutf), gw.x, s);
            s = fmaf(gelu_interp(acch[rr*4+1] + accl[rr*4+1], s_lutf), gw.y, s);
            s = fmaf(gelu_interp(acch[rr*4+2] + accl[rr*4+2], s_lutf), gw.z, s);
            s = fmaf(gelu_interp(acch[rr*4+3] + accl[rr*4+3], s_lutf), gw.w, s);
        }
        accp = fmaf(s, wgt, accp);
    }

    // combine the two j-halves (lane and lane^32 share the same p)
    float v = accp + __shfl_xor(accp, 32, 64);
    if (half == 0) s_red[wid][row] = fmaf(g3bias, wsum, v);
    __syncthreads();
    if (tid < 32) {
        float sum = s_red[0][tid] + s_red[1][tid] + s_red[2][tid] + s_red[3][tid];
        ucp[(nh*B + b)*P_TOTAL + p0 + tid] = sum * (1.0f/NBC);
    }
}

// ---------------------------------------------------------------------------
// Kernel C: combine n-half partials + bilinear align_corners upsample
// ---------------------------------------------------------------------------
__global__ void bg_upsample(const float* __restrict__ ucp, float* __restrict__ out) {
    int idx = blockIdx.x * 256 + threadIdx.x;
    if (idx >= B*HOUT*WOUT) return;
    int x = idx & (WOUT-1);
    int y = (idx >> 8) & (HOUT-1);
    int b = idx >> 16;
    float fy = (float)y * ((float)(HC-1)/(float)(HOUT-1));
    float fx = (float)x * ((float)(WC-1)/(float)(WOUT-1));
    int y0 = (int)floorf(fy);
    int x0 = (int)floorf(fx);
    int y1 = min(y0+1, HC-1);
    int x1 = min(x0+1, WC-1);
    float wy = fy - (float)y0;
    float wx = fx - (float)x0;
    const float* u0 = ucp + b*P_TOTAL;
    const float* u1 = ucp + (B + b)*P_TOTAL;
    float v00 = u0[y0*WC+x0] + u1[y0*WC+x0];
    float v01 = u0[y0*WC+x1] + u1[y0*WC+x1];
    float v10 = u0[y1*WC+x0] + u1[y1*WC+x0];
    float v11 = u0[y1*WC+x1] + u1[y1*WC+x1];
    float top = v00 + (v01 - v00)*wx;
    float bot = v10 + (v11 - v10)*wx;
    out[idx] = top + (bot - top)*wy;
}

extern "C" void kernel_launch(void* const* d_in, const int* in_sizes, int n_in,
                              void* d_out, int out_size, void* d_ws, size_t ws_size,
                              hipStream_t stream) {
    const float* bi  = (const float*)d_in[0];
    const float* e1w = (const float*)d_in[2];
    const float* e1b = (const float*)d_in[3];
    const float* e2w = (const float*)d_in[4];
    const float* e2b = (const float*)d_in[5];
    const float* g1w = (const float*)d_in[6];
    const float* g1b = (const float*)d_in[7];
    const float* g2w = (const float*)d_in[8];
    const float* g2b = (const float*)d_in[9];
    const float* g3w = (const float*)d_in[10];
    const float* g3b = (const float*)d_in[11];
    const float* ds  = (const float*)d_in[12];
    float* out = (float*)d_out;

    float* bfg = (float*)d_ws;                 // B*NBC*HID floats
    float* ucp = bfg + B*NBC*HID;              // 2*B*P_TOTAL floats (partials)

    bg_encode<<<dim3(B*NBC), dim3(64), 0, stream>>>(bi, e1w, e1b, e2w, e2b, g1w, g1b, bfg);
    bg_main<<<dim3(P_TOTAL/32, B, 2), dim3(256), 0, stream>>>(bi, g1w, g2w, g2b, g3w, g3b, ds, bfg, ucp);
    bg_upsample<<<dim3((B*HOUT*WOUT)/256), dim3(256), 0, stream>>>(ucp, out);
}

// Round 8
// 60.393 us; speedup vs baseline: 3.2585x; 1.2542x over previous
//
#include <hip/hip_runtime.h>
#include <math.h>

#define B 4
#define NBC 128
#define HID 64
#define HC 64
#define WC 64
#define P_TOTAL (HC*WC)
#define HOUT 256
#define WOUT 256

typedef __attribute__((ext_vector_type(8)))  short bs8;   // 8 bf16 (4 VGPRs) MFMA A/B frag
typedef __attribute__((ext_vector_type(16))) float fx16;  // 32x32 MFMA C/D frag

// Fast exact-gelu: erf via 3-term Abramowitz-Stegun 7.1.25 (|err| <= 2.5e-5).
// Used in bg_encode and to build the LUT nodes.
__device__ __forceinline__ float gelu_fast(float x) {
    float y = fabsf(x) * 0.70710678118654752f;
    float t = __builtin_amdgcn_rcpf(fmaf(0.47047f, y, 1.0f));
    float p = fmaf(t, 0.7478556f, -0.0958798f);
    p = fmaf(t, p, 0.3480242f);
    p = p * t;
    float e = __expf(-y * y);
    float er = fmaf(-p, e, 1.0f);
    float s = copysignf(er, x);
    float hx = 0.5f * x;
    return fmaf(hx, s, hx);
}

// fp32 -> bf16 bits, round-half-up
__device__ __forceinline__ short f2bf(float f) {
    return (short)((__float_as_uint(f) + 0x8000u) >> 16);
}
__device__ __forceinline__ float bf2f(short h) {
    return __uint_as_float(((unsigned)(unsigned short)h) << 16);
}

// ---------------------------------------------------------------------------
// Kernel A: per-(b,n) boundary encoder + fold bfg = bf @ g1w_f + g1b.
// Output PRE-SCALED by 128 (the h1 LUT index scale) so bg_main's inner loop
// computes the LUT index directly with no per-call rescale fma.
// ---------------------------------------------------------------------------
__global__ void bg_encode(const float* __restrict__ bi,
                          const float* __restrict__ e1w, const float* __restrict__ e1b,
                          const float* __restrict__ e2w, const float* __restrict__ e2b,
                          const float* __restrict__ g1w, const float* __restrict__ g1b,
                          float* __restrict__ bfg) {
    int bn = blockIdx.x;
    int h  = threadIdx.x;
    __shared__ float t1[HID];
    __shared__ float t2[HID];
    float x = bi[bn*3+0], y = bi[bn*3+1], z = bi[bn*3+2];
    float a = x*e1w[0*HID+h] + y*e1w[1*HID+h] + z*e1w[2*HID+h] + e1b[h];
    t1[h] = gelu_fast(a);
    __syncthreads();
    float s = e2b[h];
    #pragma unroll
    for (int k = 0; k < HID; ++k) s += t1[k]*e2w[k*HID+h];
    t2[h] = gelu_fast(s);
    __syncthreads();
    float o = g1b[h];
    #pragma unroll
    for (int k = 0; k < HID; ++k) o += t2[k]*g1w[k*HID+h];
    bfg[bn*HID+h] = o * 128.0f;                  // pre-scaled for LUT indexing
}

// ---------------------------------------------------------------------------
// Kernel B: main contraction. Grid (128 p-tiles, B, 2 n-halves), block 256.
// Swapped MFMA: D[j][p] = (g2w^T)(h1^T) -> lane's C column = p = lane&31.
// h1 gelu: nearest-bf16-bits LDS LUT over [-16,16], h=1/128 (4096 nodes);
// index computed directly from pre-scaled operands (no per-call rescale,
// no tail guard -- med3 clamp lands escapes on gelu(+-16), exact in bf16).
// h2 gelu: f32 interp LUT over [-16,16], h=1/32 (1025 nodes, err 1.2e-4).
// launch_bounds(256,2): (256,4) caused scratch spill (round 4). VGPR <= 128.
// ---------------------------------------------------------------------------
__global__ __launch_bounds__(256, 2) void bg_main(
    const float* __restrict__ bi,
    const float* __restrict__ g1w,     // rows 64,65 = g1w_c ; row 66 = g1w_d
    const float* __restrict__ g2w,     // [64][32]
    const float* __restrict__ g2b,     // [32]
    const float* __restrict__ g3w,     // [32]
    const float* __restrict__ g3b,     // [1]
    const float* __restrict__ dscale,  // [1]
    const float* __restrict__ bfg,     // [B*NBC][HID], pre-scaled x128
    float* __restrict__ ucp)           // [2][B][P_TOTAL] partials
{
    const int b    = blockIdx.y;
    const int nh   = blockIdx.z;       // n-half: 0 or 1
    const int p0   = blockIdx.x * 32;
    const int tid  = threadIdx.x;
    const int lane = tid & 63;
    const int wid  = tid >> 6;         // 0..3
    const int row  = lane & 31;        // p column of C
    const int half = lane >> 5;        // k/j sub-block

    __shared__ float s_bfg[64][HID];           // 16 KB (x128 pre-scaled)
    __shared__ float s_cg[32][65];             // 8.32 KB: cg*128 + 2048
    __shared__ unsigned short s_lut16[4096];   // 8 KB: bf16-bits gelu, nearest, [-16,16]
    __shared__ float s_lutf[1025];             // 4.1 KB: f32 gelu, interp, [-16,16]
    __shared__ float s_bcx[64], s_bcy[64];
    __shared__ float s_g1d[HID];               // g1d*128
    __shared__ float s_g2b[32], s_g3w[32];
    __shared__ float s_red[4][32];

    {   // stage this n-half's bfg rows (coalesced float4, already scaled)
        const float4* src = (const float4*)(bfg + (b*NBC + nh*64)*HID);
        float4* dst = (float4*)(&s_bfg[0][0]);
        #pragma unroll
        for (int i = 0; i < 4; ++i)
            dst[tid + i*256] = src[tid + i*256];
    }
    if (tid < 64) {
        int ng = b*NBC + nh*64 + tid;
        s_bcx[tid] = bi[ng*3+0];
        s_bcy[tid] = bi[ng*3+1];
        s_g1d[tid] = g1w[66*HID + tid] * 128.0f;
    }
    if (tid >= 64 && tid < 96)  s_g2b[tid-64] = g2b[tid-64];
    if (tid >= 96 && tid < 128) s_g3w[tid-96] = g3w[tid-96];
    #pragma unroll
    for (int i = 0; i < 8; ++i) {               // cg tile: 2048 items, pre-scaled
        int idx = tid + i*256;
        int pl = idx >> 6, k = idx & 63;
        int pp = p0 + pl;
        float gxx = -1.0f + (2.0f/(WC-1)) * (float)(pp & (WC-1));
        float gyy = -1.0f + (2.0f/(HC-1)) * (float)(pp >> 6);
        s_cg[pl][k] = fmaf(gxx*g1w[64*HID+k] + gyy*g1w[65*HID+k], 128.0f, 2048.0f);
    }
    #pragma unroll
    for (int i = 0; i < 16; ++i) {              // bf16 nearest table (half-shifted nodes)
        int idx = tid + i*256;
        float node = fmaf((float)idx, 0.0078125f, -15.99609375f);  // -16 + (i+0.5)/128
        s_lut16[idx] = (unsigned short)((__float_as_uint(gelu_fast(node)) + 0x8000u) >> 16);
    }
    for (int i = tid; i < 1025; i += 256)       // f32 interp table, h=1/32
        s_lutf[i] = gelu_fast(fmaf((float)i, 0.03125f, -16.0f));

    // g2w^T fragments (A operand), hi+lo bf16 split for accuracy
    bs8 whi[4], wlo[4];
    #pragma unroll
    for (int m = 0; m < 4; ++m) {
        #pragma unroll
        for (int e = 0; e < 8; ++e) {
            int k = m*16 + half*8 + e;
            float w = g2w[k*32 + row];
            short hi = f2bf(w);
            whi[m][e] = hi;
            wlo[m][e] = f2bf(w - bf2f(hi));
        }
    }
    __syncthreads();

    const int p = p0 + row;
    const float gx = -1.0f + (2.0f/(WC-1)) * (float)(p & (WC-1));
    const float gy = -1.0f + (2.0f/(HC-1)) * (float)(p >> 6);
    const float as = fabsf(dscale[0]);
    const float g3bias = g3b[0];

    float accp = 0.0f, wsum = 0.0f;

    for (int ni = 0; ni < 16; ++ni) {
        const int n = wid*16 + ni;              // block-local boundary index
        float dx = s_bcx[n] - gx;
        float dy = s_bcy[n] - gy;
        float dist = sqrtf(fmaf(dx, dx, fmaf(dy, dy, 1e-8f)));
        float wgt = __expf(-as * dist);
        wsum += wgt;

        fx16 acch, accl;                         // two independent MFMA chains
        #pragma unroll
        for (int rr = 0; rr < 4; ++rr) {
            float4 bias = *(const float4*)&s_g2b[rr*8 + half*4];
            acch[rr*4+0] = bias.x; acch[rr*4+1] = bias.y;
            acch[rr*4+2] = bias.z; acch[rr*4+3] = bias.w;
            accl[rr*4+0] = 0.0f;  accl[rr*4+1] = 0.0f;
            accl[rr*4+2] = 0.0f;  accl[rr*4+3] = 0.0f;
        }

        #pragma unroll
        for (int m = 0; m < 4; ++m) {
            bs8 af;                              // B operand: h1^T, col = p
            #pragma unroll
            for (int e = 0; e < 8; ++e) {
                int k = m*16 + half*8 + e;
                // xi = (bfg + cg + dist*g1d)*128 + 2048, built from pre-scaled terms
                float xi = s_bfg[n][k] + fmaf(dist, s_g1d[k], s_cg[row][k]);
                xi = fminf(fmaxf(xi, 0.0f), 4095.0f);     // v_med3
                af[e] = (short)s_lut16[(int)xi];          // ds_read_u16: bf16 bits
            }
            acch = __builtin_amdgcn_mfma_f32_32x32x16_bf16(whi[m], af, acch, 0, 0, 0);
            accl = __builtin_amdgcn_mfma_f32_32x32x16_bf16(wlo[m], af, accl, 0, 0, 0);
        }

        float s = 0.0f;
        #pragma unroll
        for (int rr = 0; rr < 4; ++rr) {
            float4 gw = *(const float4*)&s_g3w[rr*8 + half*4];
            #pragma unroll
            for (int q = 0; q < 4; ++q) {
                float h2 = acch[rr*4+q] + accl[rr*4+q];
                float xi = fmaf(h2, 32.0f, 512.0f);
                xi = fminf(fmaxf(xi, 0.0f), 1023.99f);
                int i = (int)xi;
                float f = __builtin_amdgcn_fractf(xi);
                float a = s_lutf[i];
                float bb = s_lutf[i + 1];
                float g = fmaf(f, bb - a, a);
                s = fmaf(g, ((const float*)&gw)[q], s);
            }
        }
        accp = fmaf(s, wgt, accp);
    }

    // combine the two j-halves (lane and lane^32 share the same p)
    float v = accp + __shfl_xor(accp, 32, 64);
    if (half == 0) s_red[wid][row] = fmaf(g3bias, wsum, v);
    __syncthreads();
    if (tid < 32) {
        float sum = s_red[0][tid] + s_red[1][tid] + s_red[2][tid] + s_red[3][tid];
        ucp[(nh*B + b)*P_TOTAL + p0 + tid] = sum * (1.0f/NBC);
    }
}

// ---------------------------------------------------------------------------
// Kernel C: combine n-half partials + bilinear align_corners upsample
// ---------------------------------------------------------------------------
__global__ void bg_upsample(const float* __restrict__ ucp, float* __restrict__ out) {
    int idx = blockIdx.x * 256 + threadIdx.x;
    if (idx >= B*HOUT*WOUT) return;
    int x = idx & (WOUT-1);
    int y = (idx >> 8) & (HOUT-1);
    int b = idx >> 16;
    float fy = (float)y * ((float)(HC-1)/(float)(HOUT-1));
    float fx = (float)x * ((float)(WC-1)/(float)(WOUT-1));
    int y0 = (int)floorf(fy);
    int x0 = (int)floorf(fx);
    int y1 = min(y0+1, HC-1);
    int x1 = min(x0+1, WC-1);
    float wy = fy - (float)y0;
    float wx = fx - (float)x0;
    const float* u0 = ucp + b*P_TOTAL;
    const float* u1 = ucp + (B + b)*P_TOTAL;
    float v00 = u0[y0*WC+x0] + u1[y0*WC+x0];
    float v01 = u0[y0*WC+x1] + u1[y0*WC+x1];
    float v10 = u0[y1*WC+x0] + u1[y1*WC+x0];
    float v11 = u0[y1*WC+x1] + u1[y1*WC+x1];
    float top = v00 + (v01 - v00)*wx;
    float bot = v10 + (v11 - v10)*wx;
    out[idx] = top + (bot - top)*wy;
}

extern "C" void kernel_launch(void* const* d_in, const int* in_sizes, int n_in,
                              void* d_out, int out_size, void* d_ws, size_t ws_size,
                              hipStream_t stream) {
    const float* bi  = (const float*)d_in[0];
    const float* e1w = (const float*)d_in[2];
    const float* e1b = (const float*)d_in[3];
    const float* e2w = (const float*)d_in[4];
    const float* e2b = (const float*)d_in[5];
    const float* g1w = (const float*)d_in[6];
    const float* g1b = (const float*)d_in[7];
    const float* g2w = (const float*)d_in[8];
    const float* g2b = (const float*)d_in[9];
    const float* g3w = (const float*)d_in[10];
    const float* g3b = (const float*)d_in[11];
    const float* ds  = (const float*)d_in[12];
    float* out = (float*)d_out;

    float* bfg = (float*)d_ws;                 // B*NBC*HID floats (x128 scaled)
    float* ucp = bfg + B*NBC*HID;              // 2*B*P_TOTAL floats (partials)

    bg_encode<<<dim3(B*NBC), dim3(64), 0, stream>>>(bi, e1w, e1b, e2w, e2b, g1w, g1b, bfg);
    bg_main<<<dim3(P_TOTAL/32, B, 2), dim3(256), 0, stream>>>(bi, g1w, g2w, g2b, g3w, g3b, ds, bfg, ucp);
    bg_upsample<<<dim3((B*HOUT*WOUT)/256), dim3(256), 0, stream>>>(ucp, out);
}

// Round 9
// 56.694 us; speedup vs baseline: 3.4711x; 1.0652x over previous
//
#include <hip/hip_runtime.h>
#include <math.h>

#define B 4
#define NBC 128
#define HID 64
#define HC 64
#define WC 64
#define P_TOTAL (HC*WC)
#define HOUT 256
#define WOUT 256

typedef __attribute__((ext_vector_type(8)))  short bs8;   // 8 bf16 (4 VGPRs) MFMA A/B frag
typedef __attribute__((ext_vector_type(16))) float fx16;  // 32x32 MFMA C/D frag
typedef __attribute__((ext_vector_type(2)))  float f32x2; // v_pk_*_f32 pair

// Fast exact-gelu: erf via 3-term Abramowitz-Stegun 7.1.25 (|err| <= 2.5e-5).
// Used in bg_encode and to build the LUT nodes.
__device__ __forceinline__ float gelu_fast(float x) {
    float y = fabsf(x) * 0.70710678118654752f;
    float t = __builtin_amdgcn_rcpf(fmaf(0.47047f, y, 1.0f));
    float p = fmaf(t, 0.7478556f, -0.0958798f);
    p = fmaf(t, p, 0.3480242f);
    p = p * t;
    float e = __expf(-y * y);
    float er = fmaf(-p, e, 1.0f);
    float s = copysignf(er, x);
    float hx = 0.5f * x;
    return fmaf(hx, s, hx);
}

// fp32 -> bf16 bits, round-half-up
__device__ __forceinline__ short f2bf(float f) {
    return (short)((__float_as_uint(f) + 0x8000u) >> 16);
}
__device__ __forceinline__ float bf2f(short h) {
    return __uint_as_float(((unsigned)(unsigned short)h) << 16);
}

// ---------------------------------------------------------------------------
// Kernel A: per-(b,n) boundary encoder + fold bfg = bf @ g1w_f + g1b.
// Output PRE-SCALED by 128 (the LUT index scale).
// ---------------------------------------------------------------------------
__global__ void bg_encode(const float* __restrict__ bi,
                          const float* __restrict__ e1w, const float* __restrict__ e1b,
                          const float* __restrict__ e2w, const float* __restrict__ e2b,
                          const float* __restrict__ g1w, const float* __restrict__ g1b,
                          float* __restrict__ bfg) {
    int bn = blockIdx.x;
    int h  = threadIdx.x;
    __shared__ float t1[HID];
    __shared__ float t2[HID];
    float x = bi[bn*3+0], y = bi[bn*3+1], z = bi[bn*3+2];
    float a = x*e1w[0*HID+h] + y*e1w[1*HID+h] + z*e1w[2*HID+h] + e1b[h];
    t1[h] = gelu_fast(a);
    __syncthreads();
    float s = e2b[h];
    #pragma unroll
    for (int k = 0; k < HID; ++k) s += t1[k]*e2w[k*HID+h];
    t2[h] = gelu_fast(s);
    __syncthreads();
    float o = g1b[h];
    #pragma unroll
    for (int k = 0; k < HID; ++k) o += t2[k]*g1w[k*HID+h];
    bfg[bn*HID+h] = o * 128.0f;                  // pre-scaled for LUT indexing
}

// ---------------------------------------------------------------------------
// Kernel B: main contraction. Grid (128 p-tiles, B, 2 n-halves), block 256.
// Swapped MFMA: D[j][p] = (g2w^T)(h1^T) -> lane's C column = p = lane&31.
// ONE bf16-bits nearest LUT over [-16,16], h=1/128 (4096 u16) serves BOTH
// h1 and h2 gelu (h2 value re-expanded via <<16). Index chains in f32x2 so
// the compiler can emit v_pk_fma/add/min/max (2 elems/instr, gfx90a+).
// s_cg stride 66: float2 loads 8B-aligned; bank map (2r+k)%32 -> 2-way (free).
// launch_bounds(256,2): (256,4) caused scratch spill (round 4). VGPR <= 128.
// ---------------------------------------------------------------------------
__global__ __launch_bounds__(256, 2) void bg_main(
    const float* __restrict__ bi,
    const float* __restrict__ g1w,     // rows 64,65 = g1w_c ; row 66 = g1w_d
    const float* __restrict__ g2w,     // [64][32]
    const float* __restrict__ g2b,     // [32]
    const float* __restrict__ g3w,     // [32]
    const float* __restrict__ g3b,     // [1]
    const float* __restrict__ dscale,  // [1]
    const float* __restrict__ bfg,     // [B*NBC][HID], pre-scaled x128
    float* __restrict__ ucp)           // [2][B][P_TOTAL] partials
{
    const int b    = blockIdx.y;
    const int nh   = blockIdx.z;       // n-half: 0 or 1
    const int p0   = blockIdx.x * 32;
    const int tid  = threadIdx.x;
    const int lane = tid & 63;
    const int wid  = tid >> 6;         // 0..3
    const int row  = lane & 31;        // p column of C
    const int half = lane >> 5;        // k/j sub-block

    __shared__ float s_bfg[64][HID];           // 16 KB (x128 pre-scaled)
    __shared__ float s_cg[32][66];             // 8.45 KB: cg*128 + 2048, stride 66
    __shared__ unsigned short s_lut16[4096];   // 8 KB: bf16-bits gelu, nearest, [-16,16]
    __shared__ float s_bcx[64], s_bcy[64];
    __shared__ float s_g1d[HID];               // g1d*128
    __shared__ float s_g2b[32], s_g3w[32];
    __shared__ float s_red[4][32];

    {   // stage this n-half's bfg rows (coalesced float4, already scaled)
        const float4* src = (const float4*)(bfg + (b*NBC + nh*64)*HID);
        float4* dst = (float4*)(&s_bfg[0][0]);
        #pragma unroll
        for (int i = 0; i < 4; ++i)
            dst[tid + i*256] = src[tid + i*256];
    }
    if (tid < 64) {
        int ng = b*NBC + nh*64 + tid;
        s_bcx[tid] = bi[ng*3+0];
        s_bcy[tid] = bi[ng*3+1];
        s_g1d[tid] = g1w[66*HID + tid] * 128.0f;
    }
    if (tid >= 64 && tid < 96)  s_g2b[tid-64] = g2b[tid-64];
    if (tid >= 96 && tid < 128) s_g3w[tid-96] = g3w[tid-96];
    #pragma unroll
    for (int i = 0; i < 8; ++i) {               // cg tile: 2048 items, pre-scaled
        int idx = tid + i*256;
        int pl = idx >> 6, k = idx & 63;
        int pp = p0 + pl;
        float gxx = -1.0f + (2.0f/(WC-1)) * (float)(pp & (WC-1));
        float gyy = -1.0f + (2.0f/(HC-1)) * (float)(pp >> 6);
        s_cg[pl][k] = fmaf(gxx*g1w[64*HID+k] + gyy*g1w[65*HID+k], 128.0f, 2048.0f);
    }
    #pragma unroll
    for (int i = 0; i < 16; ++i) {              // bf16 nearest table (half-shifted nodes)
        int idx = tid + i*256;
        float node = fmaf((float)idx, 0.0078125f, -15.99609375f);  // -16 + (i+0.5)/128
        s_lut16[idx] = (unsigned short)((__float_as_uint(gelu_fast(node)) + 0x8000u) >> 16);
    }

    // g2w^T fragments (A operand), hi+lo bf16 split for accuracy
    bs8 whi[4], wlo[4];
    #pragma unroll
    for (int m = 0; m < 4; ++m) {
        #pragma unroll
        for (int e = 0; e < 8; ++e) {
            int k = m*16 + half*8 + e;
            float w = g2w[k*32 + row];
            short hi = f2bf(w);
            whi[m][e] = hi;
            wlo[m][e] = f2bf(w - bf2f(hi));
        }
    }
    __syncthreads();

    const int p = p0 + row;
    const float gx = -1.0f + (2.0f/(WC-1)) * (float)(p & (WC-1));
    const float gy = -1.0f + (2.0f/(HC-1)) * (float)(p >> 6);
    const float as = fabsf(dscale[0]);
    const float g3bias = g3b[0];

    const f32x2 kZero2 = {0.0f, 0.0f};
    const f32x2 kMax2  = {4095.0f, 4095.0f};
    const f32x2 kScale2 = {128.0f, 128.0f};
    const f32x2 kOff2   = {2048.0f, 2048.0f};

    float accp = 0.0f, wsum = 0.0f;

    for (int ni = 0; ni < 16; ++ni) {
        const int n = wid*16 + ni;              // block-local boundary index
        float dx = s_bcx[n] - gx;
        float dy = s_bcy[n] - gy;
        float dist = sqrtf(fmaf(dx, dx, fmaf(dy, dy, 1e-8f)));
        float wgt = __expf(-as * dist);
        wsum += wgt;
        f32x2 dist2 = {dist, dist};

        fx16 acch, accl;                         // two independent MFMA chains
        #pragma unroll
        for (int rr = 0; rr < 4; ++rr) {
            float4 bias = *(const float4*)&s_g2b[rr*8 + half*4];
            acch[rr*4+0] = bias.x; acch[rr*4+1] = bias.y;
            acch[rr*4+2] = bias.z; acch[rr*4+3] = bias.w;
            accl[rr*4+0] = 0.0f;  accl[rr*4+1] = 0.0f;
            accl[rr*4+2] = 0.0f;  accl[rr*4+3] = 0.0f;
        }

        #pragma unroll
        for (int m = 0; m < 4; ++m) {
            const int kb = m*16 + half*8;
            const f32x2* bfg2 = (const f32x2*)&s_bfg[n][kb];
            const f32x2* g1d2 = (const f32x2*)&s_g1d[kb];
            const f32x2* cg2  = (const f32x2*)&s_cg[row][kb];
            bs8 af;                              // B operand: h1^T, col = p
            #pragma unroll
            for (int pr = 0; pr < 4; ++pr) {
                // xi = (bfg + cg + dist*g1d)*128 + 2048, all pre-scaled -> pk ops
                f32x2 xi2 = bfg2[pr] + (dist2 * g1d2[pr] + cg2[pr]);
                xi2 = __builtin_elementwise_min(__builtin_elementwise_max(xi2, kZero2), kMax2);
                af[2*pr+0] = (short)s_lut16[(int)xi2.x];   // ds_read_u16: bf16 bits
                af[2*pr+1] = (short)s_lut16[(int)xi2.y];
            }
            acch = __builtin_amdgcn_mfma_f32_32x32x16_bf16(whi[m], af, acch, 0, 0, 0);
            accl = __builtin_amdgcn_mfma_f32_32x32x16_bf16(wlo[m], af, accl, 0, 0, 0);
        }

        // epilogue: gelu(h2) via the same bf16-nearest LUT, pk index math
        f32x2 s2 = {0.0f, 0.0f};
        #pragma unroll
        for (int rr = 0; rr < 4; ++rr) {
            float4 gw = *(const float4*)&s_g3w[rr*8 + half*4];
            #pragma unroll
            for (int qq = 0; qq < 4; qq += 2) {
                f32x2 h2 = f32x2{acch[rr*4+qq], acch[rr*4+qq+1]}
                         + f32x2{accl[rr*4+qq], accl[rr*4+qq+1]};
                f32x2 xi2 = h2 * kScale2 + kOff2;
                xi2 = __builtin_elementwise_min(__builtin_elementwise_max(xi2, kZero2), kMax2);
                f32x2 g2v;
                g2v.x = __uint_as_float(((unsigned)s_lut16[(int)xi2.x]) << 16);
                g2v.y = __uint_as_float(((unsigned)s_lut16[(int)xi2.y]) << 16);
                s2 = s2 + g2v * f32x2{((const float*)&gw)[qq], ((const float*)&gw)[qq+1]};
            }
        }
        accp = fmaf(s2.x + s2.y, wgt, accp);
    }

    // combine the two j-halves (lane and lane^32 share the same p)
    float v = accp + __shfl_xor(accp, 32, 64);
    if (half == 0) s_red[wid][row] = fmaf(g3bias, wsum, v);
    __syncthreads();
    if (tid < 32) {
        float sum = s_red[0][tid] + s_red[1][tid] + s_red[2][tid] + s_red[3][tid];
        ucp[(nh*B + b)*P_TOTAL + p0 + tid] = sum * (1.0f/NBC);
    }
}

// ---------------------------------------------------------------------------
// Kernel C: combine n-half partials + bilinear align_corners upsample
// ---------------------------------------------------------------------------
__global__ void bg_upsample(const float* __restrict__ ucp, float* __restrict__ out) {
    int idx = blockIdx.x * 256 + threadIdx.x;
    if (idx >= B*HOUT*WOUT) return;
    int x = idx & (WOUT-1);
    int y = (idx >> 8) & (HOUT-1);
    int b = idx >> 16;
    float fy = (float)y * ((float)(HC-1)/(float)(HOUT-1));
    float fx = (float)x * ((float)(WC-1)/(float)(WOUT-1));
    int y0 = (int)floorf(fy);
    int x0 = (int)floorf(fx);
    int y1 = min(y0+1, HC-1);
    int x1 = min(x0+1, WC-1);
    float wy = fy - (float)y0;
    float wx = fx - (float)x0;
    const float* u0 = ucp + b*P_TOTAL;
    const float* u1 = ucp + (B + b)*P_TOTAL;
    float v00 = u0[y0*WC+x0] + u1[y0*WC+x0];
    float v01 = u0[y0*WC+x1] + u1[y0*WC+x1];
    float v10 = u0[y1*WC+x0] + u1[y1*WC+x0];
    float v11 = u0[y1*WC+x1] + u1[y1*WC+x1];
    float top = v00 + (v01 - v00)*wx;
    float bot = v10 + (v11 - v10)*wx;
    out[idx] = top + (bot - top)*wy;
}

extern "C" void kernel_launch(void* const* d_in, const int* in_sizes, int n_in,
                              void* d_out, int out_size, void* d_ws, size_t ws_size,
                              hipStream_t stream) {
    const float* bi  = (const float*)d_in[0];
    const float* e1w = (const float*)d_in[2];
    const float* e1b = (const float*)d_in[3];
    const float* e2w = (const float*)d_in[4];
    const float* e2b = (const float*)d_in[5];
    const float* g1w = (const float*)d_in[6];
    const float* g1b = (const float*)d_in[7];
    const float* g2w = (const float*)d_in[8];
    const float* g2b = (const float*)d_in[9];
    const float* g3w = (const float*)d_in[10];
    const float* g3b = (const float*)d_in[11];
    const float* ds  = (const float*)d_in[12];
    float* out = (float*)d_out;

    float* bfg = (float*)d_ws;                 // B*NBC*HID floats (x128 scaled)
    float* ucp = bfg + B*NBC*HID;              // 2*B*P_TOTAL floats (partials)

    bg_encode<<<dim3(B*NBC), dim3(64), 0, stream>>>(bi, e1w, e1b, e2w, e2b, g1w, g1b, bfg);
    bg_main<<<dim3(P_TOTAL/32, B, 2), dim3(256), 0, stream>>>(bi, g1w, g2w, g2b, g3w, g3b, ds, bfg, ucp);
    bg_upsample<<<dim3((B*HOUT*WOUT)/256), dim3(256), 0, stream>>>(ucp, out);
}